// Round 4
// baseline (25.483 us; speedup 1.0000x reference)
//
#include <hip/hip_runtime.h>
#include <math.h>

#define WT 64             // 1 wave per block
#define PTS 8             // test points per thread
#define TILE (WT * PTS)   // 512 test points per block
#define CHUNK 32          // train rows staged per chunk

__global__ __launch_bounds__(WT) void kde_main(
    const float* __restrict__ test, const float* __restrict__ train,
    float* __restrict__ partial, int M, int N, int nsplit, float negk,
    float twok) {
  __shared__ float4 ylds[CHUNK * 2];  // 32 rows x 8 floats
  __shared__ float blds[CHUNK];       // -k*||y||^2

  int tile = blockIdx.x / nsplit;
  int split = blockIdx.x - tile * nsplit;
  int lane = threadIdx.x;

  // Load 8 test points per thread (coalesced: m = base + p*64 + lane).
  const float4* xp = reinterpret_cast<const float4*>(test);
  float4 x0[PTS], x1[PTS];
  float a[PTS], acc[PTS];
#pragma unroll
  for (int p = 0; p < PTS; ++p) {
    int m = tile * TILE + p * WT + lane;
    int mc = min(m, M - 1);
    float4 u = xp[(size_t)mc * 2];
    float4 v = xp[(size_t)mc * 2 + 1];
    a[p] = negk * (u.x * u.x + u.y * u.y + u.z * u.z + u.w * u.w +
                   v.x * v.x + v.y * v.y + v.z * v.z + v.w * v.w);
    // prescale by 2k so per-row arg = a[p] + b_j + dot(x', y_j)
    u.x *= twok; u.y *= twok; u.z *= twok; u.w *= twok;
    v.x *= twok; v.y *= twok; v.z *= twok; v.w *= twok;
    x0[p] = u;
    x1[p] = v;
    acc[p] = 0.0f;
  }

  int nchunks = (N + CHUNK - 1) / CHUNK;
  for (int c = split; c < nchunks; c += nsplit) {
    int j0 = c * CHUNK;
    int nrow = min(CHUNK, N - j0);

    __syncthreads();  // cheap: single wave
    int idx = 2 * j0 + lane;
    if (idx < 2 * N) ylds[lane] = reinterpret_cast<const float4*>(train)[idx];
    __syncthreads();
    if (lane < nrow) {
      float4 y0 = ylds[2 * lane], y1 = ylds[2 * lane + 1];
      blds[lane] = negk * (y0.x * y0.x + y0.y * y0.y + y0.z * y0.z +
                           y0.w * y0.w + y1.x * y1.x + y1.y * y1.y +
                           y1.z * y1.z + y1.w * y1.w);
    }
    __syncthreads();

#define BODY(r)                                               \
  {                                                           \
    float4 y0 = ylds[2 * (r)], y1 = ylds[2 * (r) + 1];        \
    float bj = blds[(r)];                                     \
    _Pragma("unroll") for (int p = 0; p < PTS; ++p) {         \
      float g = fmaf(x0[p].x, y0.x, a[p] + bj);               \
      g = fmaf(x0[p].y, y0.y, g);                             \
      g = fmaf(x0[p].z, y0.z, g);                             \
      g = fmaf(x0[p].w, y0.w, g);                             \
      g = fmaf(x1[p].x, y1.x, g);                             \
      g = fmaf(x1[p].y, y1.y, g);                             \
      g = fmaf(x1[p].z, y1.z, g);                             \
      g = fmaf(x1[p].w, y1.w, g);                             \
      acc[p] += __builtin_amdgcn_exp2f(g);                    \
    }                                                         \
  }

    if (nrow == CHUNK) {
#pragma unroll 2
      for (int r = 0; r < CHUNK; ++r) BODY(r);
    } else {
      for (int r = 0; r < nrow; ++r) BODY(r);
    }
#undef BODY
  }

#pragma unroll
  for (int p = 0; p < PTS; ++p) {
    int m = tile * TILE + p * WT + lane;
    if (m < M) partial[(size_t)split * M + m] = acc[p];
  }
}

// Two-level reduce in one kernel: block handles 16 consecutive m.
// Thread (g = tid>>4, ml = tid&15) sums its i-slice for m = mbase+ml,
// then 16x16 LDS transpose-sum finalizes.
__global__ __launch_bounds__(256) void kde_reduce(
    const float* __restrict__ partial, float* __restrict__ out, int M,
    int nsplit, float scale) {
  __shared__ float lds[16][17];
  int mbase = blockIdx.x * 16;
  int g = threadIdx.x >> 4;
  int ml = threadIdx.x & 15;
  int m = mbase + ml;
  int npg = (nsplit + 15) / 16;

  float s = 0.0f;
  if (m < M) {
    int i0 = g * npg;
    int i1 = min(nsplit, i0 + npg);
    for (int i = i0; i < i1; ++i) s += partial[(size_t)i * M + m];
  }
  lds[g][ml] = s;
  __syncthreads();
  if (threadIdx.x < 16) {
    int mm = mbase + threadIdx.x;
    if (mm < M) {
      float t = 0.0f;
#pragma unroll
      for (int gg = 0; gg < 16; ++gg) t += lds[gg][threadIdx.x];
      out[mm] = scale * t;
    }
  }
}

extern "C" void kernel_launch(void* const* d_in, const int* in_sizes, int n_in,
                              void* d_out, int out_size, void* d_ws,
                              size_t ws_size, hipStream_t stream) {
  const float* test = (const float*)d_in[0];
  const float* train = (const float*)d_in[1];
  float* out = (float*)d_out;
  int M = in_sizes[0] / 8;
  int N = in_sizes[1] / 8;

  const double var = 0.05 * 0.05;
  const double k = 1.4426950408889634 / (2.0 * var);  // log2(e)/(2 var)
  const float negk = (float)(-k);
  const float twok = (float)(2.0 * k);
  const float coef = (float)(1.0 / sqrt(2.0 * M_PI * var));
  const float scale = coef / (float)N;

  // ws layout: [ partial : nsplit*M floats ]
  int nsplit = 256;
  size_t avail = ws_size / sizeof(float);
  while (nsplit > 1 && (size_t)nsplit * (size_t)M > avail) nsplit >>= 1;
  float* partial = (float*)d_ws;

  int ntiles = (M + TILE - 1) / TILE;
  kde_main<<<ntiles * nsplit, WT, 0, stream>>>(test, train, partial, M, N,
                                               nsplit, negk, twok);
  kde_reduce<<<(M + 15) / 16, 256, 0, stream>>>(partial, out, M, nsplit,
                                                scale);
}

// Round 5
// 19.134 us; speedup vs baseline: 1.3318x; 1.3318x over previous
//
#include <hip/hip_runtime.h>
#include <math.h>

#define THREADS 256
#define PTS 8  // test points per block

// One fused kernel: block b owns test points [8b, 8b+8); every thread streams
// a stride-256 interleaved slice of ALL train rows (L2-resident, coalesced),
// accumulating 8 partial sums; block-level LDS+shuffle reduce writes out[].
// exp(-||x-y||^2 * k') computed as exp2(a + b_j + dot(2k*x, y)) with
// a = -k*||x||^2, b_j = -k*||y_j||^2, k = log2(e)/(2*var).
__global__ __launch_bounds__(THREADS, 2) void kde_fused(
    const float* __restrict__ test, const float* __restrict__ train,
    float* __restrict__ out, int M, int N, float negk, float twok,
    float scale) {
  __shared__ float lds[PTS][THREADS];

  const int t = threadIdx.x;
  const int mbase = blockIdx.x * PTS;

  // Block-uniform test-point loads; prescale by 2k.
  float x[PTS][8];
  float a[PTS], acc[PTS];
#pragma unroll
  for (int p = 0; p < PTS; ++p) {
    const float4* xr = reinterpret_cast<const float4*>(test) +
                       (size_t)min(mbase + p, M - 1) * 2;
    float4 u = xr[0], v = xr[1];
    a[p] = negk * (u.x * u.x + u.y * u.y + u.z * u.z + u.w * u.w +
                   v.x * v.x + v.y * v.y + v.z * v.z + v.w * v.w);
    x[p][0] = u.x * twok; x[p][1] = u.y * twok;
    x[p][2] = u.z * twok; x[p][3] = u.w * twok;
    x[p][4] = v.x * twok; x[p][5] = v.y * twok;
    x[p][6] = v.z * twok; x[p][7] = v.w * twok;
    acc[p] = 0.f;
  }

  const float4* tp = reinterpret_cast<const float4*>(train);
#pragma unroll 2
  for (int r = t; r < N; r += THREADS) {
    float4 y0 = tp[(size_t)r * 2];
    float4 y1 = tp[(size_t)r * 2 + 1];
    float sy = y0.x * y0.x + y0.y * y0.y + y0.z * y0.z + y0.w * y0.w +
               y1.x * y1.x + y1.y * y1.y + y1.z * y1.z + y1.w * y1.w;
    float b = negk * sy;
#pragma unroll
    for (int p = 0; p < PTS; ++p) {
      float g = fmaf(x[p][0], y0.x, a[p] + b);
      g = fmaf(x[p][1], y0.y, g);
      g = fmaf(x[p][2], y0.z, g);
      g = fmaf(x[p][3], y0.w, g);
      g = fmaf(x[p][4], y1.x, g);
      g = fmaf(x[p][5], y1.y, g);
      g = fmaf(x[p][6], y1.z, g);
      g = fmaf(x[p][7], y1.w, g);
      acc[p] += __builtin_amdgcn_exp2f(g);
    }
  }

  // Block reduce: 256 partials -> 1 per point (fixed order, deterministic).
#pragma unroll
  for (int p = 0; p < PTS; ++p) lds[p][t] = acc[p];
  __syncthreads();
  const int w = t >> 6;
  const int lane = t & 63;
  for (int p = w; p < PTS; p += THREADS / 64) {
    float s = lds[p][lane] + lds[p][lane + 64] + lds[p][lane + 128] +
              lds[p][lane + 192];
#pragma unroll
    for (int off = 32; off > 0; off >>= 1) s += __shfl_down(s, off);
    if (lane == 0) {
      int m = mbase + p;
      if (m < M) out[m] = scale * s;
    }
  }
}

extern "C" void kernel_launch(void* const* d_in, const int* in_sizes, int n_in,
                              void* d_out, int out_size, void* d_ws,
                              size_t ws_size, hipStream_t stream) {
  const float* test = (const float*)d_in[0];
  const float* train = (const float*)d_in[1];
  float* out = (float*)d_out;
  int M = in_sizes[0] / 8;
  int N = in_sizes[1] / 8;

  const double var = 0.05 * 0.05;
  const double k = 1.4426950408889634 / (2.0 * var);  // log2(e)/(2 var)
  const float negk = (float)(-k);
  const float twok = (float)(2.0 * k);
  const float coef = (float)(1.0 / sqrt(2.0 * M_PI * var));
  const float scale = coef / (float)N;

  int nblocks = (M + PTS - 1) / PTS;
  kde_fused<<<nblocks, THREADS, 0, stream>>>(test, train, out, M, N, negk,
                                             twok, scale);
}